// Round 1
// baseline (398.976 us; speedup 1.0000x reference)
//
#include <hip/hip_runtime.h>
#include <math.h>

#define S 4096
#define H 32
#define D 128
#define IMP 4
#define RECENT 512
#define KEEP (IMP + RECENT)      // 516
#define SELECT (S - RECENT)      // 3584

#define RCHUNKS 128
#define ROWS_TOTAL (H * S)                 // 131072
#define ROWS_PER (ROWS_TOTAL / RCHUNKS)    // 1024

// ---------------- Kernel 1: partial column sums of (H*S, S) fp32 matrix ----
// grid: (4, RCHUNKS), block: 256. Each thread owns one float4 column group.
__global__ __launch_bounds__(256) void colsum_partial(const float* __restrict__ attn,
                                                      float* __restrict__ partials) {
    const int jc  = blockIdx.x;            // 0..3
    const int rc  = blockIdx.y;            // 0..RCHUNKS-1
    const int tid = threadIdx.x;           // 0..255
    const int j4  = jc * 256 + tid;        // float4 column index 0..1023

    const float4* p = reinterpret_cast<const float4*>(attn)
                    + (size_t)rc * ROWS_PER * (S / 4) + j4;
    float4 acc = make_float4(0.f, 0.f, 0.f, 0.f);
    #pragma unroll 8
    for (int r = 0; r < ROWS_PER; ++r) {
        float4 v = p[(size_t)r * (S / 4)];
        acc.x += v.x; acc.y += v.y; acc.z += v.z; acc.w += v.w;
    }
    reinterpret_cast<float4*>(partials)[(size_t)rc * (S / 4) + j4] = acc;
}

// ---------------- Kernel 2: reduce partials -> imp_score (mean over heads) --
__global__ __launch_bounds__(256) void reduce_partials(const float* __restrict__ partials,
                                                       float* __restrict__ imp) {
    const int j = blockIdx.x * 256 + threadIdx.x;   // 0..4095
    float s = 0.f;
    #pragma unroll 8
    for (int rc = 0; rc < RCHUNKS; ++rc) s += partials[(size_t)rc * S + j];
    imp[j] = s * (1.0f / (float)H);
}

// ---------------- Kernel 3: top-4 (tie-break low index) + small outputs -----
__global__ __launch_bounds__(256) void topk_and_small(const float* __restrict__ imp,
                                                      int* __restrict__ keep_idx,
                                                      float* __restrict__ imp_out,
                                                      float* __restrict__ counter_out) {
    __shared__ float svals[256];
    __shared__ int   sidx[256];
    __shared__ int   chosen[IMP];
    const int tid = threadIdx.x;

    for (int k = 0; k < IMP; ++k) {
        float best = -INFINITY;
        int   bidx = 0x7fffffff;
        for (int j = tid; j < SELECT; j += 256) {
            bool skip = false;
            for (int t = 0; t < k; ++t) if (chosen[t] == j) skip = true;
            if (skip) continue;
            float v = imp[j];
            if (v > best || (v == best && j < bidx)) { best = v; bidx = j; }
        }
        svals[tid] = best; sidx[tid] = bidx;
        __syncthreads();
        for (int off = 128; off > 0; off >>= 1) {
            if (tid < off) {
                float v2 = svals[tid + off]; int i2 = sidx[tid + off];
                if (v2 > svals[tid] || (v2 == svals[tid] && i2 < sidx[tid])) {
                    svals[tid] = v2; sidx[tid] = i2;
                }
            }
            __syncthreads();
        }
        if (tid == 0) chosen[k] = sidx[0];
        __syncthreads();
    }

    // sort the 4 chosen indices ascending (thread 0, tiny)
    if (tid == 0) {
        for (int a = 0; a < IMP; ++a)
            for (int b = a + 1; b < IMP; ++b)
                if (chosen[b] < chosen[a]) { int t = chosen[a]; chosen[a] = chosen[b]; chosen[b] = t; }
    }
    __syncthreads();

    for (int n = tid; n < KEEP; n += 256) {
        const int j = (n < IMP) ? chosen[n] : (SELECT + (n - IMP));
        keep_idx[n]    = j;                      // consumed by gather kernel
        imp_out[n]     = imp[j];
        counter_out[n] = (float)(S - j);
    }
}

// ---------------- Kernel 4: gather K/V rows ---------------------------------
// total float4 elements: 2 * H * KEEP * (D/4) = 1,056,768  -> 4128 blocks x 256
__global__ __launch_bounds__(256) void gather_kv(const float* __restrict__ k_cache,
                                                 const float* __restrict__ v_cache,
                                                 const int* __restrict__ keep_idx,
                                                 float* __restrict__ out) {
    const int PER = H * KEEP * (D / 4);          // 528384 float4 per tensor
    const int gid = blockIdx.x * 256 + threadIdx.x;
    if (gid >= 2 * PER) return;

    const int which = gid / PER;                 // 0 = K, 1 = V
    int rem = gid - which * PER;
    const int h  = rem / (KEEP * (D / 4));
    rem -= h * (KEEP * (D / 4));
    const int n  = rem / (D / 4);
    const int d4 = rem - n * (D / 4);

    const int row = keep_idx[n];
    const float* src = which ? v_cache : k_cache;
    float4 v = reinterpret_cast<const float4*>(src)[((size_t)h * S + row) * (D / 4) + d4];
    reinterpret_cast<float4*>(out)[(size_t)which * PER + ((size_t)h * KEEP + n) * (D / 4) + d4] = v;
}

extern "C" void kernel_launch(void* const* d_in, const int* in_sizes, int n_in,
                              void* d_out, int out_size, void* d_ws, size_t ws_size,
                              hipStream_t stream) {
    const float* k_cache = (const float*)d_in[0];
    const float* v_cache = (const float*)d_in[1];
    const float* attn    = (const float*)d_in[2];
    float* out = (float*)d_out;

    // workspace layout (fp32 elements): partials[RCHUNKS*S] | imp[S] | keep_idx[KEEP]
    float* partials = (float*)d_ws;
    float* imp      = partials + (size_t)RCHUNKS * S;
    int*   keep_idx = (int*)(imp + S);

    float* k_out       = out;
    float* imp_out     = out + (size_t)2 * H * KEEP * D;
    float* counter_out = imp_out + KEEP;
    (void)k_out; (void)in_sizes; (void)n_in; (void)out_size; (void)ws_size;

    colsum_partial<<<dim3(4, RCHUNKS), 256, 0, stream>>>(attn, partials);
    reduce_partials<<<dim3(S / 256), 256, 0, stream>>>(partials, imp);
    topk_and_small<<<1, 256, 0, stream>>>(imp, keep_idx, imp_out, counter_out);
    gather_kv<<<dim3(2 * H * KEEP * (D / 4) / 256), 256, 0, stream>>>(k_cache, v_cache, keep_idx, out);
}